// Round 12
// baseline (226.281 us; speedup 1.0000x reference)
//
#include <hip/hip_runtime.h>

typedef short bf16x8 __attribute__((ext_vector_type(8)));
typedef float f32x16 __attribute__((ext_vector_type(16)));
typedef int   i32x4  __attribute__((ext_vector_type(4)));

#define INV_SQRT165 0.07784989441615349f
#define FINAL_SCALE 0.0032113081446662823f   /* sqrt(165)/4000 */
#define ZERO16 ((f32x16){0.f,0.f,0.f,0.f,0.f,0.f,0.f,0.f,0.f,0.f,0.f,0.f,0.f,0.f,0.f,0.f})

__device__ __forceinline__ unsigned short f2bf(float f) {
  unsigned int u = __builtin_bit_cast(unsigned int, f);
  unsigned int r = (u + 0x7FFFu + ((u >> 16) & 1u)) >> 16;
  return (unsigned short)r;
}
__device__ __forceinline__ float bf2f(unsigned short h) {
  unsigned int u = ((unsigned int)h) << 16;
  return __builtin_bit_cast(float, u);
}

__device__ __forceinline__ void gl_lds16(const void* g, void* l) {
  __builtin_amdgcn_global_load_lds(
      (const __attribute__((address_space(1))) unsigned int*)(unsigned long long)g,
      (__attribute__((address_space(3))) unsigned int*)(unsigned int)(unsigned long long)l,
      16, 0, 0);
}

__device__ __forceinline__ void decode_i(int i, int& lv, int& rel) {
  if (i < 1)       { lv = 0; rel = i; }
  else if (i < 10) { lv = 1; rel = i - 1; }
  else if (i < 35) { lv = 2; rel = i - 10; }
  else if (i < 84) { lv = 3; rel = i - 35; }
  else             { lv = 4; rel = i - 84; }
}
__device__ __forceinline__ int divq(int rel, int lv) {   // rel / (2lv+1), rel < 81
  const int mag[5] = {32768, 10923, 6554, 4682, 3641};
  return (rel * mag[lv]) >> 15;
}

// E-row permutation: row p holds actual g = G(p) so GEMM1's C/D register order IS
// GEMM2's A-frag k-slot order (no cross-lane exchange).
__device__ __forceinline__ int gperm(int p) {
  int a = p & 3, hlp = (p >> 2) & 1, c = p >> 3;
  return ((c >> 1) << 4) + hlp * 8 + ((c & 1) << 2) + a;
}

// ---------------- prep ----------------
// blocks 0..511: (ci = bx>>2, yg = bx&3) Da chunk -> E-fold for 4 y; yg==0 also d2pre.
// blocks 512..583: ewpre. blocks 584..594: psi2.
__global__ __launch_bounds__(256) void prep_k(const float* __restrict__ Da,
                                              const float* __restrict__ ew,
                                              const float* __restrict__ Y,
                                              const float* __restrict__ w_s2,
                                              const float* __restrict__ Dk,
                                              const float* __restrict__ w_so3,
                                              unsigned short* __restrict__ e1pre,
                                              unsigned short* __restrict__ d2pre,
                                              unsigned short* __restrict__ ewpre,
                                              float* __restrict__ psi2) {
  __shared__ __align__(16) unsigned short lds[13824];
  const int tid = threadIdx.x;
  const int l = tid & 63, hl = l >> 5, ln = l & 31;
  if (blockIdx.x < 512) {
    const int ci = blockIdx.x >> 2, yg = blockIdx.x & 3;
    const int g0 = ci * 32;
    float* psi1L = (float*)(lds + 6464);
    for (int e = tid; e < 6400; e += 256) lds[e] = 0;
    for (int e = tid; e < 400; e += 256) {
      int yv = e / 25, iv = e % 25;
      float s = 0.f;
      for (int n = 0; n < 48; n++) s += Y[n * 25 + iv] * w_s2[yv * 48 + n];
      psi1L[e] = s * 0.14433756729740643f;
    }
    __syncthreads();
    int rows = 4000 - g0; if (rows > 32) rows = 32; if (rows < 0) rows = 0;
    int ne = rows * 165;
    for (int e = tid; e < ne; e += 256) {
      int gl_ = e / 165, k = e - gl_ * 165;
      lds[gl_ * 200 + k] = f2bf(Da[g0 * 165 + e]);
    }
    __syncthreads();
    if (yg == 0) {
#pragma unroll
      for (int it = 0; it < 3; it++) {
        int tt = it * 4 + (tid >> 6);
        int nf = tt >> 1, gk = tt & 1;
        unsigned short v[8];
#pragma unroll
        for (int j = 0; j < 8; j++)
          v[j] = lds[(gk * 16 + hl * 8 + j) * 200 + nf * 32 + ln];
        *(i32x4*)(d2pre + ci * 6144 + tt * 512 + l * 8) = *(i32x4*)v;
      }
    }
    for (int yi = 0; yi < 4; yi++) {
      int yy = yg * 4 + yi;
#pragma unroll
      for (int it = 0; it < 4; it++) {
        int idx = it * 256 + tid;
        int kf = idx >> 9, r2 = idx & 511;
        int ll = r2 >> 3, j = r2 & 7;
        int lnn = ll & 31, hll = ll >> 5;
        int k = kf * 16 + hll * 8 + j;
        unsigned short ov = 0;
        if (k < 25) {
          int lv = (k < 1) ? 0 : (k < 4) ? 1 : (k < 9) ? 2 : (k < 16) ? 3 : 4;
          int d = 2 * lv + 1;
          int m = k - lv * lv;
          int off165 = lv * (4 * lv * lv - 1) / 3;   // {0,1,10,35,84}
          int gp = gperm(lnn);
          float s = 0.f;
          const float* pr = psi1L + yy * 25 + lv * lv;
          const unsigned short* dr = lds + gp * 200 + off165 + m;
          for (int j2 = 0; j2 < d; j2++) s += pr[j2] * bf2f(dr[j2 * d]);
          ov = f2bf(s * INV_SQRT165);
        }
        e1pre[((yy * 128 + ci) * 2 + kf) * 512 + ll * 8 + j] = ov;
      }
    }
  } else if (blockIdx.x < 584) {
    const int bx2 = blockIdx.x - 512;
    const int n0 = bx2 * 64;
    for (int e = tid; e < 13824; e += 256) lds[e] = 0;
    __syncthreads();
    for (int e = tid; e < 10560; e += 256) {
      int k = e >> 6, n = e & 63;
      lds[k * 72 + n] = f2bf(ew[k * 4608 + n0 + n]);
    }
    __syncthreads();
#pragma unroll
    for (int it = 0; it < 6; it++) {
      int tb = it * 4 + (tid >> 6);
      int nt2 = tb / 12, kf = tb - nt2 * 12;
      unsigned short v[8];
#pragma unroll
      for (int j = 0; j < 8; j++)
        v[j] = lds[(kf * 16 + hl * 8 + j) * 72 + nt2 * 32 + ln];
      *(i32x4*)(ewpre + (bx2 * 2 + nt2) * 6144 + kf * 512 + l * 8) = *(i32x4*)v;
    }
  } else {
    int t = (blockIdx.x - 584) * 256 + tid;
    if (t < 2640) {
      int ch = t / 165, i = t % 165;
      float s = 0.f;
      for (int n = 0; n < 192; n++) s += Dk[n * 165 + i] * w_so3[ch * 192 + n];
      psi2[t] = s * (0.07216878364870323f * FINAL_SCALE);
    }
  }
}

// ---------------- fused MLP: 3-deep ring + counted vmcnt (best measured: 63.6us) ----------------
// R1-R9 conclusion: 923 TF = 37% dense peak, invariant to barriers/bytes/occupancy/
// LDS/drain semantics -> structural floor of this K=32+ReLU decomposition. Frozen.
__global__ __launch_bounds__(256, 2) void fused_mlp_k(
    const float* __restrict__ x,
    const unsigned short* __restrict__ e1pre,
    const unsigned short* __restrict__ d2pre,
    unsigned short* __restrict__ part)
{
  __shared__ __align__(16) unsigned char smem[49152];   // 3 x 16KB ring
  const int tid = threadIdx.x;
  const int w = tid >> 6, l = tid & 63;
  const int hl = l >> 5, ln = l & 31;
  const int h = blockIdx.x >> 8;                 // 0..1
  const int y = (blockIdx.x >> 4) & 15;
  const int btg = blockIdx.x & 15;
  const int bt = btg * 4 + w;                    // wave owns ONE bt
  const int c0 = h * 63;                         // 125 chunks: 63 + 62
  const int cnt = h ? 62 : 63;

  // x fragments (B-operand of GEMM1): lane ln -> batch b = bt*32+ln, k pad to 32
  bf16x8 xf[2];
  {
    const float* xr = x + (bt * 32 + ln) * 25;
#pragma unroll
    for (int kf = 0; kf < 2; kf++) {
      unsigned short v[8];
#pragma unroll
      for (int j = 0; j < 8; j++) {
        int k = kf * 16 + hl * 8 + j;
        v[j] = (k < 25) ? f2bf(xr[k]) : (unsigned short)0;
      }
      xf[kf] = *(bf16x8*)v;
    }
  }

  f32x16 o[6];
#pragma unroll
  for (int i = 0; i < 6; i++) o[i] = ZERO16;

  const unsigned short* ebase = e1pre + (y * 128) * 1024;   // shorts

  // STAGE chunk (local idx lc) into ring buffer `buf`; 4 uniform DMAs per wave.
  // tb 0,1 = E; 2..13 = d2; 14,15 = pad (duplicate E srcs, never read).
#define STAGE(lc, buf) do {                                               \
    unsigned char* nb_ = smem + (buf) * 16384;                            \
    const int c_ = c0 + (lc);                                             \
    _Pragma("unroll")                                                     \
    for (int i_ = 0; i_ < 4; i_++) {                                      \
      int tb_ = w * 4 + i_;                                               \
      int st_ = (tb_ < 14) ? tb_ : (tb_ - 14);                            \
      const unsigned short* src_ = (st_ < 2)                              \
          ? ebase + c_ * 1024 + st_ * 512 + l * 8                         \
          : d2pre + c_ * 6144 + (st_ - 2) * 512 + l * 8;                  \
      gl_lds16(src_, nb_ + tb_ * 1024);                                   \
    }                                                                     \
  } while (0)

#define COMPUTE(cbp) do {                                                  \
    const unsigned char* cb_ = (cbp);                                      \
    bf16x8 eC0 = *(const bf16x8*)(cb_ + l * 16);                           \
    bf16x8 eC1 = *(const bf16x8*)(cb_ + 1024 + l * 16);                    \
    f32x16 s = ZERO16;                                                     \
    s = __builtin_amdgcn_mfma_f32_32x32x16_bf16(eC0, xf[0], s, 0, 0, 0);   \
    s = __builtin_amdgcn_mfma_f32_32x32x16_bf16(eC1, xf[1], s, 0, 0, 0);   \
    unsigned int dw[8];                                                    \
    _Pragma("unroll")                                                      \
    for (int p_ = 0; p_ < 8; p_++) {                                       \
      float lo = fmaxf(s[2 * p_], 0.f), hi = fmaxf(s[2 * p_ + 1], 0.f);    \
      asm("v_cvt_pk_bf16_f32 %0, %1, %2" : "=v"(dw[p_]) : "v"(lo), "v"(hi)); \
    }                                                                      \
    bf16x8 a20 = __builtin_bit_cast(bf16x8,                                \
        (i32x4){(int)dw[0], (int)dw[1], (int)dw[2], (int)dw[3]});          \
    bf16x8 a21 = __builtin_bit_cast(bf16x8,                                \
        (i32x4){(int)dw[4], (int)dw[5], (int)dw[6], (int)dw[7]});          \
    _Pragma("unroll")                                                      \
    for (int gk = 0; gk < 2; gk++) {                                       \
      bf16x8 a2 = gk ? a21 : a20;                                          \
      _Pragma("unroll")                                                    \
      for (int nf = 0; nf < 6; nf++) {                                     \
        bf16x8 b2 = *(const bf16x8*)(cb_ + 2048 + (nf * 2 + gk) * 1024 + l * 16); \
        o[nf] = __builtin_amdgcn_mfma_f32_32x32x16_bf16(a2, b2, o[nf], 0, 0, 0);  \
      }                                                                    \
    }                                                                      \
  } while (0)

  // prologue: stage chunks 0 and 1 (cnt >= 62 > 1 always)
  STAGE(0, 0);
  STAGE(1, 1);

  int bufc = 0;
  for (int ci = 0; ci < cnt - 1; ci++) {
    // chunk ci's 4 DMAs (oldest) must land; chunk ci+1's 4 stay in flight
    asm volatile("s_waitcnt vmcnt(4)" ::: "memory");
    asm volatile("s_waitcnt lgkmcnt(0)" ::: "memory");   // my reads of reuse-buffer done
    __builtin_amdgcn_s_barrier();                        // all waves' chunk-ci DMAs done
    if (ci + 2 < cnt) {
      int bn = bufc + 2; if (bn >= 3) bn -= 3;
      STAGE(ci + 2, bn);
    }
    COMPUTE(smem + bufc * 16384);
    bufc = (bufc == 2) ? 0 : bufc + 1;
  }
  // peeled last iteration: full drain
  asm volatile("s_waitcnt vmcnt(0)" ::: "memory");
  asm volatile("s_waitcnt lgkmcnt(0)" ::: "memory");
  __builtin_amdgcn_s_barrier();
  COMPUTE(smem + bufc * 16384);

#undef STAGE
#undef COMPUTE

  // store partials: part[((h*16+y)*2048 + b)*192 + n]   (32 slices = 25.2 MB)
  unsigned short* pp = part + (size_t)((h * 16 + y) * 2048 + bt * 32) * 192;
#pragma unroll
  for (int nf = 0; nf < 6; nf++) {
    int n = nf * 32 + ln;
    if (n < 176) {
#pragma unroll
      for (int r = 0; r < 16; r++) {
        int row = (r & 3) + 8 * (r >> 2) + 4 * hl;
        pp[row * 192 + n] = f2bf(o[nf][r]);
      }
    }
  }
}

// ---------------- partial reduce (2 halves) + so3_to_so3 (psi2 in LDS) ----------------
__global__ __launch_bounds__(256) void so3_k(const unsigned short* __restrict__ part,
                                             const float* __restrict__ psi2,
                                             float* __restrict__ harm_out,
                                             unsigned short* __restrict__ harmbpre) {
  __shared__ float lds[4 * 16 * 180];
  __shared__ float p2s[2640];
  const int tid = threadIdx.x;
  const int b0 = blockIdx.x * 4;
  for (int e = tid; e < 2640; e += 256) p2s[e] = psi2[e];
  {
    const int ybl = tid >> 2;
    const int yy = ybl & 15, bloc = ybl >> 4;
    const int s = tid & 3;
    const unsigned int* r0 = (const unsigned int*)(part + ((size_t)(0 * 16 + yy) * 2048 + b0 + bloc) * 192);
    const unsigned int* r1 = (const unsigned int*)(part + ((size_t)(1 * 16 + yy) * 2048 + b0 + bloc) * 192);
    float* dst = lds + (bloc * 16 + yy) * 180;
#pragma unroll
    for (int t = 0; t < 22; t++) {
      int d = s * 22 + t;
      if (d < 88) {
        unsigned int u0 = r0[d], u1 = r1[d];
        int n0 = d * 2;
        dst[n0]     = bf2f((unsigned short)(u0 & 0xFFFF)) + bf2f((unsigned short)(u1 & 0xFFFF));
        dst[n0 + 1] = bf2f((unsigned short)(u0 >> 16)) + bf2f((unsigned short)(u1 >> 16));
      }
    }
  }
  __syncthreads();
  for (int jj = tid; jj < 768; jj += 256) {
    int e = (jj * 683) >> 17;              // jj / 192
    int i = jj - e * 192;
    int bb = b0 + e;
    unsigned short* hb = harmbpre + (((bb >> 5) * 12 + (i >> 4)) << 9)
                       + ((i >> 3) & 1) * 256 + (bb & 31) * 8 + (i & 7);
    if (i < 165) {
      const float* row0 = lds + e * (16 * 180);
      int lv, rel; decode_i(i, lv, rel);
      int d = 2 * lv + 1;
      int off = i - rel;
      int v = divq(rel, lv), m = rel - v * d;
      float s = 0.f;
      for (int ch = 0; ch < 16; ch++) {
        const float* rw = row0 + ch * 180 + off;
        const float* p2 = p2s + ch * 165 + off;
        for (int u = 0; u < d; u++) s += rw[u * d + m] * p2[u * d + v];
      }
      s *= 0.25f * rsqrtf((float)d);
      harm_out[bb * 165 + i] = s;
      *hb = f2bf(s);
    } else {
      *hb = 0;
    }
  }
}

// ---------------- eval pass A: GEMM -> per-(row,colblock) softmax stats ----------------
// No logits materialization (saves 75 MB round-trip). acc accumulation order is
// IDENTICAL to probsC_k -> bit-identical acc (MFMA deterministic), so the
// threshold-equality semantics of the old eval+smthresh flow are preserved.
__global__ __launch_bounds__(64) void evalA_k(
    const unsigned short* __restrict__ harmbpre,
    const unsigned short* __restrict__ ewpre,
    float* __restrict__ stats,         // [2048][24][2] (m, s) — overlays probs region
    float* __restrict__ logit0)
{
  const int l = threadIdx.x;
  const int hl = l >> 5, ln = l & 31;
  const int mt = blockIdx.y;
  const int cb = blockIdx.x;

  bf16x8 a[12];
  const short* ap = (const short*)harmbpre + mt * 6144 + l * 8;
#pragma unroll
  for (int kf = 0; kf < 12; kf++) a[kf] = *(const bf16x8*)(ap + kf * 512);

  f32x16 acc[6];
#pragma unroll
  for (int nf = 0; nf < 6; nf++) acc[nf] = ZERO16;

  const short* bp = (const short*)ewpre + (cb * 6) * 6144 + l * 8;
#pragma unroll
  for (int kf = 0; kf < 12; kf++) {
#pragma unroll
    for (int nf = 0; nf < 6; nf++) {
      bf16x8 b = *(const bf16x8*)(bp + nf * 6144 + kf * 512);
      acc[nf] = __builtin_amdgcn_mfma_f32_32x32x16_bf16(a[kf], b, acc[nf], 0, 0, 0);
    }
  }
  if (mt == 0 && hl == 0) {
#pragma unroll
    for (int nf = 0; nf < 6; nf++) logit0[cb * 192 + nf * 32 + ln] = acc[nf][0];
  }
  // per-row (m, s) over this block's 192 cols; butterfly stays within 32-lane half
#pragma unroll
  for (int r = 0; r < 16; r++) {
    int row = (r & 3) + 8 * (r >> 2) + 4 * hl;
    float m = acc[0][r];
#pragma unroll
    for (int nf = 1; nf < 6; nf++) m = fmaxf(m, acc[nf][r]);
#pragma unroll
    for (int off = 16; off >= 1; off >>= 1) m = fmaxf(m, __shfl_xor(m, off));
    float s = 0.f;
#pragma unroll
    for (int nf = 0; nf < 6; nf++) s += __expf(acc[nf][r] - m);
#pragma unroll
    for (int off = 16; off >= 1; off >>= 1) s += __shfl_xor(s, off);
    if (ln == 0) {
      float2 v2; v2.x = m; v2.y = s;
      *(float2*)&stats[((mt * 32 + row) * 24 + cb) * 2] = v2;
    }
  }
}

// ---------------- finalize: per-row stat combine + fifth (single block) ----------------
__global__ __launch_bounds__(256) void finalize_k(const float* __restrict__ logit0,
                                                  const float* __restrict__ stats,
                                                  float* __restrict__ rowstats,
                                                  float* __restrict__ fifth) {
  __shared__ float buf[4608];
  __shared__ float sm[4], ss[4];
  __shared__ float wv[4]; __shared__ int wi[4];
  __shared__ float gbest;
  const int tid = threadIdx.x;
  const int l = tid & 63, w = tid >> 6;
  // phase 2: combine 24 (m,s) pairs per row -> (M, 1/S) with rescale identity
  for (int row = tid; row < 2048; row += 256) {
    const float2* st = (const float2*)(stats + row * 48);
    float M = -3.4e38f;
#pragma unroll
    for (int j = 0; j < 24; j++) M = fmaxf(M, st[j].x);
    float S = 0.f;
#pragma unroll
    for (int j = 0; j < 24; j++) { float2 v = st[j]; S += v.y * __expf(v.x - M); }
    rowstats[row * 2] = M; rowstats[row * 2 + 1] = 1.f / S;
  }
  // phase 1: fifth from logit0 (exact same computation as proven fifth_k)
  float v[18];
  float mx = -3.4e38f;
#pragma unroll
  for (int i = 0; i < 18; i++) {
    v[i] = logit0[i * 256 + tid];
    buf[i * 256 + tid] = v[i];
    mx = fmaxf(mx, v[i]);
  }
#pragma unroll
  for (int off = 32; off >= 1; off >>= 1) mx = fmaxf(mx, __shfl_xor(mx, off));
  if (l == 0) sm[w] = mx;
  __syncthreads();
  mx = fmaxf(fmaxf(sm[0], sm[1]), fmaxf(sm[2], sm[3]));
  float s = 0.f;
#pragma unroll
  for (int i = 0; i < 18; i++) s += __expf(v[i] - mx);
#pragma unroll
  for (int off = 32; off >= 1; off >>= 1) s += __shfl_xor(s, off);
  if (l == 0) ss[w] = s;
  __syncthreads();
  s = ss[0] + ss[1] + ss[2] + ss[3];
  float inv = 1.f / s;
  // row 0 must use EXACTLY these (mx, inv) so pv(5th) == t in probsC
  if (tid == 0) { rowstats[0] = mx; rowstats[1] = inv; }

  float ff = 0.f;
  for (int it = 0; it < 5; it++) {
    float bm = -3.4e38f; int bi = 0;
    for (int i = tid; i < 4608; i += 256) {
      float xx = buf[i];
      if (xx > bm) { bm = xx; bi = i; }
    }
    for (int off = 32; off >= 1; off >>= 1) {
      float ov = __shfl_xor(bm, off); int oi = __shfl_xor(bi, off);
      if (ov > bm) { bm = ov; bi = oi; }
    }
    if (l == 0) { wv[w] = bm; wi[w] = bi; }
    __syncthreads();
    if (tid == 0) {
      float B = wv[0]; int I = wi[0];
      for (int k = 1; k < 4; k++) if (wv[k] > B) { B = wv[k]; I = wi[k]; }
      gbest = B;
      buf[I] = -3.4e38f;
    }
    __syncthreads();
    ff = gbest;
    __syncthreads();
  }
  if (tid == 0) *fifth = __expf(ff - mx) * inv;
}

// ---------------- eval pass C: recompute GEMM, write thresholded probs directly ----------------
__global__ __launch_bounds__(64) void probsC_k(
    const unsigned short* __restrict__ harmbpre,
    const unsigned short* __restrict__ ewpre,
    const float* __restrict__ rowstats,
    const float* __restrict__ fifth,
    float* __restrict__ probs)
{
  const int l = threadIdx.x;
  const int hl = l >> 5, ln = l & 31;
  const int mt = blockIdx.y;
  const int n0 = blockIdx.x * 192;

  bf16x8 a[12];
  const short* ap = (const short*)harmbpre + mt * 6144 + l * 8;
#pragma unroll
  for (int kf = 0; kf < 12; kf++) a[kf] = *(const bf16x8*)(ap + kf * 512);

  f32x16 acc[6];
#pragma unroll
  for (int nf = 0; nf < 6; nf++) acc[nf] = ZERO16;

  const short* bp = (const short*)ewpre + (blockIdx.x * 6) * 6144 + l * 8;
#pragma unroll
  for (int kf = 0; kf < 12; kf++) {
#pragma unroll
    for (int nf = 0; nf < 6; nf++) {
      bf16x8 b = *(const bf16x8*)(bp + nf * 6144 + kf * 512);
      acc[nf] = __builtin_amdgcn_mfma_f32_32x32x16_bf16(a[kf], b, acc[nf], 0, 0, 0);
    }
  }
  const float t = *fifth;
#pragma unroll
  for (int r = 0; r < 16; r++) {
    int row = (r & 3) + 8 * (r >> 2) + 4 * hl;
    int grow = mt * 32 + row;
    float2 ms = *(const float2*)&rowstats[grow * 2];
    float* pr = probs + (size_t)grow * 4608 + n0;
#pragma unroll
    for (int nf = 0; nf < 6; nf++) {
      float pv = __expf(acc[nf][r] - ms.x) * ms.y;
      pr[nf * 32 + ln] = (pv < t) ? 0.f : pv;
    }
  }
}

extern "C" void kernel_launch(void* const* d_in, const int* in_sizes, int n_in,
                              void* d_out, int out_size, void* d_ws, size_t ws_size,
                              hipStream_t stream) {
  const float* x     = (const float*)d_in[0];
  const float* w_s2  = (const float*)d_in[1];
  const float* Y     = (const float*)d_in[2];
  const float* w_so3 = (const float*)d_in[3];
  const float* Dk    = (const float*)d_in[4];
  const float* Da    = (const float*)d_in[5];
  const float* ew    = (const float*)d_in[6];

  float* out = (float*)d_out;
  float* harm_out = out;                 // 2048*165
  float* probs    = out + 337920;        // 2048*4608 (partials -> stats -> probs)
  unsigned short* part = (unsigned short*)probs;   // 32 slices = 25.2 MB
  float* stats    = probs;               // 393 KB overlay: written after part dies,
                                         // read by finalize, then overwritten by probsC

  char* ws = (char*)d_ws;
  float* psi2  = (float*)(ws + 0);                         // 10,560 B
  float* fifth = (float*)(ws + 10560);                     // 4 B
  unsigned short* e1pre    = (unsigned short*)(ws + 12288);      // 4,194,304 B
  unsigned short* d2pre    = (unsigned short*)(ws + 4206592);    // 1,572,864 B
  unsigned short* ewpre    = (unsigned short*)(ws + 5779456);    // 1,769,472 B
  unsigned short* harmbpre = (unsigned short*)(ws + 7548928);    // 786,432 B
  float* logit0   = (float*)(ws + 8335360);                      // 18,432 B
  float* rowstats = (float*)(ws + 8353792);                      // 16,384 B (~8.37 MB)

  prep_k<<<595, 256, 0, stream>>>(Da, ew, Y, w_s2, Dk, w_so3, e1pre, d2pre, ewpre, psi2);
  fused_mlp_k<<<512, 256, 0, stream>>>(x, e1pre, d2pre, part);
  so3_k<<<512, 256, 0, stream>>>(part, psi2, harm_out, harmbpre);
  evalA_k<<<dim3(24, 64), 64, 0, stream>>>(harmbpre, ewpre, stats, logit0);
  finalize_k<<<1, 256, 0, stream>>>(logit0, stats, rowstats, fifth);
  probsC_k<<<dim3(24, 64), 64, 0, stream>>>(harmbpre, ewpre, rowstats, fifth, probs);
}

// Round 13
// 205.087 us; speedup vs baseline: 1.1033x; 1.1033x over previous
//
#include <hip/hip_runtime.h>

typedef short bf16x8 __attribute__((ext_vector_type(8)));
typedef float f32x16 __attribute__((ext_vector_type(16)));
typedef int   i32x4  __attribute__((ext_vector_type(4)));

#define INV_SQRT165 0.07784989441615349f
#define FINAL_SCALE 0.0032113081446662823f   /* sqrt(165)/4000 */
#define ZERO16 ((f32x16){0.f,0.f,0.f,0.f,0.f,0.f,0.f,0.f,0.f,0.f,0.f,0.f,0.f,0.f,0.f,0.f})

__device__ __forceinline__ unsigned short f2bf(float f) {
  unsigned int u = __builtin_bit_cast(unsigned int, f);
  unsigned int r = (u + 0x7FFFu + ((u >> 16) & 1u)) >> 16;
  return (unsigned short)r;
}
__device__ __forceinline__ float bf2f(unsigned short h) {
  unsigned int u = ((unsigned int)h) << 16;
  return __builtin_bit_cast(float, u);
}

__device__ __forceinline__ void gl_lds16(const void* g, void* l) {
  __builtin_amdgcn_global_load_lds(
      (const __attribute__((address_space(1))) unsigned int*)(unsigned long long)g,
      (__attribute__((address_space(3))) unsigned int*)(unsigned int)(unsigned long long)l,
      16, 0, 0);
}

__device__ __forceinline__ void decode_i(int i, int& lv, int& rel) {
  if (i < 1)       { lv = 0; rel = i; }
  else if (i < 10) { lv = 1; rel = i - 1; }
  else if (i < 35) { lv = 2; rel = i - 10; }
  else if (i < 84) { lv = 3; rel = i - 35; }
  else             { lv = 4; rel = i - 84; }
}
__device__ __forceinline__ int divq(int rel, int lv) {   // rel / (2lv+1), rel < 81
  const int mag[5] = {32768, 10923, 6554, 4682, 3641};
  return (rel * mag[lv]) >> 15;
}

// E-row permutation: row p holds actual g = G(p) so GEMM1's C/D register order IS
// GEMM2's A-frag k-slot order (no cross-lane exchange).
__device__ __forceinline__ int gperm(int p) {
  int a = p & 3, hlp = (p >> 2) & 1, c = p >> 3;
  return ((c >> 1) << 4) + hlp * 8 + ((c & 1) << 2) + a;
}

// ---------------- prep ----------------
// blocks 0..511: (ci = bx>>2, yg = bx&3) Da chunk -> E-fold for 4 y; yg==0 also d2pre.
// blocks 512..583: ewpre. blocks 584..594: psi2.
__global__ __launch_bounds__(256) void prep_k(const float* __restrict__ Da,
                                              const float* __restrict__ ew,
                                              const float* __restrict__ Y,
                                              const float* __restrict__ w_s2,
                                              const float* __restrict__ Dk,
                                              const float* __restrict__ w_so3,
                                              unsigned short* __restrict__ e1pre,
                                              unsigned short* __restrict__ d2pre,
                                              unsigned short* __restrict__ ewpre,
                                              float* __restrict__ psi2) {
  __shared__ __align__(16) unsigned short lds[13824];
  const int tid = threadIdx.x;
  const int l = tid & 63, hl = l >> 5, ln = l & 31;
  if (blockIdx.x < 512) {
    const int ci = blockIdx.x >> 2, yg = blockIdx.x & 3;
    const int g0 = ci * 32;
    float* psi1L = (float*)(lds + 6464);
    for (int e = tid; e < 6400; e += 256) lds[e] = 0;
    for (int e = tid; e < 400; e += 256) {
      int yv = e / 25, iv = e % 25;
      float s = 0.f;
      for (int n = 0; n < 48; n++) s += Y[n * 25 + iv] * w_s2[yv * 48 + n];
      psi1L[e] = s * 0.14433756729740643f;
    }
    __syncthreads();
    int rows = 4000 - g0; if (rows > 32) rows = 32; if (rows < 0) rows = 0;
    int ne = rows * 165;
    for (int e = tid; e < ne; e += 256) {
      int gl_ = e / 165, k = e - gl_ * 165;
      lds[gl_ * 200 + k] = f2bf(Da[g0 * 165 + e]);
    }
    __syncthreads();
    if (yg == 0) {
#pragma unroll
      for (int it = 0; it < 3; it++) {
        int tt = it * 4 + (tid >> 6);
        int nf = tt >> 1, gk = tt & 1;
        unsigned short v[8];
#pragma unroll
        for (int j = 0; j < 8; j++)
          v[j] = lds[(gk * 16 + hl * 8 + j) * 200 + nf * 32 + ln];
        *(i32x4*)(d2pre + ci * 6144 + tt * 512 + l * 8) = *(i32x4*)v;
      }
    }
    for (int yi = 0; yi < 4; yi++) {
      int yy = yg * 4 + yi;
#pragma unroll
      for (int it = 0; it < 4; it++) {
        int idx = it * 256 + tid;
        int kf = idx >> 9, r2 = idx & 511;
        int ll = r2 >> 3, j = r2 & 7;
        int lnn = ll & 31, hll = ll >> 5;
        int k = kf * 16 + hll * 8 + j;
        unsigned short ov = 0;
        if (k < 25) {
          int lv = (k < 1) ? 0 : (k < 4) ? 1 : (k < 9) ? 2 : (k < 16) ? 3 : 4;
          int d = 2 * lv + 1;
          int m = k - lv * lv;
          int off165 = lv * (4 * lv * lv - 1) / 3;   // {0,1,10,35,84}
          int gp = gperm(lnn);
          float s = 0.f;
          const float* pr = psi1L + yy * 25 + lv * lv;
          const unsigned short* dr = lds + gp * 200 + off165 + m;
          for (int j2 = 0; j2 < d; j2++) s += pr[j2] * bf2f(dr[j2 * d]);
          ov = f2bf(s * INV_SQRT165);
        }
        e1pre[((yy * 128 + ci) * 2 + kf) * 512 + ll * 8 + j] = ov;
      }
    }
  } else if (blockIdx.x < 584) {
    const int bx2 = blockIdx.x - 512;
    const int n0 = bx2 * 64;
    for (int e = tid; e < 13824; e += 256) lds[e] = 0;
    __syncthreads();
    for (int e = tid; e < 10560; e += 256) {
      int k = e >> 6, n = e & 63;
      lds[k * 72 + n] = f2bf(ew[k * 4608 + n0 + n]);
    }
    __syncthreads();
#pragma unroll
    for (int it = 0; it < 6; it++) {
      int tb = it * 4 + (tid >> 6);
      int nt2 = tb / 12, kf = tb - nt2 * 12;
      unsigned short v[8];
#pragma unroll
      for (int j = 0; j < 8; j++)
        v[j] = lds[(kf * 16 + hl * 8 + j) * 72 + nt2 * 32 + ln];
      *(i32x4*)(ewpre + (bx2 * 2 + nt2) * 6144 + kf * 512 + l * 8) = *(i32x4*)v;
    }
  } else {
    int t = (blockIdx.x - 584) * 256 + tid;
    if (t < 2640) {
      int ch = t / 165, i = t % 165;
      float s = 0.f;
      for (int n = 0; n < 192; n++) s += Dk[n * 165 + i] * w_so3[ch * 192 + n];
      psi2[t] = s * (0.07216878364870323f * FINAL_SCALE);
    }
  }
}

// ---------------- fused MLP: 3-deep ring + counted vmcnt (best measured: 63.6us) ----------------
// R1-R9 conclusion: 923 TF = 37% dense peak, invariant to barriers/bytes/occupancy/
// LDS/drain semantics -> structural floor of this K=32+ReLU decomposition. Frozen.
__global__ __launch_bounds__(256, 2) void fused_mlp_k(
    const float* __restrict__ x,
    const unsigned short* __restrict__ e1pre,
    const unsigned short* __restrict__ d2pre,
    unsigned short* __restrict__ part)
{
  __shared__ __align__(16) unsigned char smem[49152];   // 3 x 16KB ring
  const int tid = threadIdx.x;
  const int w = tid >> 6, l = tid & 63;
  const int hl = l >> 5, ln = l & 31;
  const int h = blockIdx.x >> 8;                 // 0..1
  const int y = (blockIdx.x >> 4) & 15;
  const int btg = blockIdx.x & 15;
  const int bt = btg * 4 + w;                    // wave owns ONE bt
  const int c0 = h * 63;                         // 125 chunks: 63 + 62
  const int cnt = h ? 62 : 63;

  // x fragments (B-operand of GEMM1): lane ln -> batch b = bt*32+ln, k pad to 32
  bf16x8 xf[2];
  {
    const float* xr = x + (bt * 32 + ln) * 25;
#pragma unroll
    for (int kf = 0; kf < 2; kf++) {
      unsigned short v[8];
#pragma unroll
      for (int j = 0; j < 8; j++) {
        int k = kf * 16 + hl * 8 + j;
        v[j] = (k < 25) ? f2bf(xr[k]) : (unsigned short)0;
      }
      xf[kf] = *(bf16x8*)v;
    }
  }

  f32x16 o[6];
#pragma unroll
  for (int i = 0; i < 6; i++) o[i] = ZERO16;

  const unsigned short* ebase = e1pre + (y * 128) * 1024;   // shorts

  // STAGE chunk (local idx lc) into ring buffer `buf`; 4 uniform DMAs per wave.
  // tb 0,1 = E; 2..13 = d2; 14,15 = pad (duplicate E srcs, never read).
#define STAGE(lc, buf) do {                                               \
    unsigned char* nb_ = smem + (buf) * 16384;                            \
    const int c_ = c0 + (lc);                                             \
    _Pragma("unroll")                                                     \
    for (int i_ = 0; i_ < 4; i_++) {                                      \
      int tb_ = w * 4 + i_;                                               \
      int st_ = (tb_ < 14) ? tb_ : (tb_ - 14);                            \
      const unsigned short* src_ = (st_ < 2)                              \
          ? ebase + c_ * 1024 + st_ * 512 + l * 8                         \
          : d2pre + c_ * 6144 + (st_ - 2) * 512 + l * 8;                  \
      gl_lds16(src_, nb_ + tb_ * 1024);                                   \
    }                                                                     \
  } while (0)

#define COMPUTE(cbp) do {                                                  \
    const unsigned char* cb_ = (cbp);                                      \
    bf16x8 eC0 = *(const bf16x8*)(cb_ + l * 16);                           \
    bf16x8 eC1 = *(const bf16x8*)(cb_ + 1024 + l * 16);                    \
    f32x16 s = ZERO16;                                                     \
    s = __builtin_amdgcn_mfma_f32_32x32x16_bf16(eC0, xf[0], s, 0, 0, 0);   \
    s = __builtin_amdgcn_mfma_f32_32x32x16_bf16(eC1, xf[1], s, 0, 0, 0);   \
    unsigned int dw[8];                                                    \
    _Pragma("unroll")                                                      \
    for (int p_ = 0; p_ < 8; p_++) {                                       \
      float lo = fmaxf(s[2 * p_], 0.f), hi = fmaxf(s[2 * p_ + 1], 0.f);    \
      asm("v_cvt_pk_bf16_f32 %0, %1, %2" : "=v"(dw[p_]) : "v"(lo), "v"(hi)); \
    }                                                                      \
    bf16x8 a20 = __builtin_bit_cast(bf16x8,                                \
        (i32x4){(int)dw[0], (int)dw[1], (int)dw[2], (int)dw[3]});          \
    bf16x8 a21 = __builtin_bit_cast(bf16x8,                                \
        (i32x4){(int)dw[4], (int)dw[5], (int)dw[6], (int)dw[7]});          \
    _Pragma("unroll")                                                      \
    for (int gk = 0; gk < 2; gk++) {                                       \
      bf16x8 a2 = gk ? a21 : a20;                                          \
      _Pragma("unroll")                                                    \
      for (int nf = 0; nf < 6; nf++) {                                     \
        bf16x8 b2 = *(const bf16x8*)(cb_ + 2048 + (nf * 2 + gk) * 1024 + l * 16); \
        o[nf] = __builtin_amdgcn_mfma_f32_32x32x16_bf16(a2, b2, o[nf], 0, 0, 0);  \
      }                                                                    \
    }                                                                      \
  } while (0)

  // prologue: stage chunks 0 and 1 (cnt >= 62 > 1 always)
  STAGE(0, 0);
  STAGE(1, 1);

  int bufc = 0;
  for (int ci = 0; ci < cnt - 1; ci++) {
    // chunk ci's 4 DMAs (oldest) must land; chunk ci+1's 4 stay in flight
    asm volatile("s_waitcnt vmcnt(4)" ::: "memory");
    asm volatile("s_waitcnt lgkmcnt(0)" ::: "memory");   // my reads of reuse-buffer done
    __builtin_amdgcn_s_barrier();                        // all waves' chunk-ci DMAs done
    if (ci + 2 < cnt) {
      int bn = bufc + 2; if (bn >= 3) bn -= 3;
      STAGE(ci + 2, bn);
    }
    COMPUTE(smem + bufc * 16384);
    bufc = (bufc == 2) ? 0 : bufc + 1;
  }
  // peeled last iteration: full drain
  asm volatile("s_waitcnt vmcnt(0)" ::: "memory");
  asm volatile("s_waitcnt lgkmcnt(0)" ::: "memory");
  __builtin_amdgcn_s_barrier();
  COMPUTE(smem + bufc * 16384);

#undef STAGE
#undef COMPUTE

  // store partials: part[((h*16+y)*2048 + b)*192 + n]   (32 slices = 25.2 MB)
  unsigned short* pp = part + (size_t)((h * 16 + y) * 2048 + bt * 32) * 192;
#pragma unroll
  for (int nf = 0; nf < 6; nf++) {
    int n = nf * 32 + ln;
    if (n < 176) {
#pragma unroll
      for (int r = 0; r < 16; r++) {
        int row = (r & 3) + 8 * (r >> 2) + 4 * hl;
        pp[row * 192 + n] = f2bf(o[nf][r]);
      }
    }
  }
}

// ---------------- partial reduce (2 halves) + so3_to_so3 (psi2 in LDS) ----------------
__global__ __launch_bounds__(256) void so3_k(const unsigned short* __restrict__ part,
                                             const float* __restrict__ psi2,
                                             float* __restrict__ harm_out,
                                             unsigned short* __restrict__ harmbpre) {
  __shared__ float lds[4 * 16 * 180];
  __shared__ float p2s[2640];
  const int tid = threadIdx.x;
  const int b0 = blockIdx.x * 4;
  for (int e = tid; e < 2640; e += 256) p2s[e] = psi2[e];
  {
    const int ybl = tid >> 2;
    const int yy = ybl & 15, bloc = ybl >> 4;
    const int s = tid & 3;
    const unsigned int* r0 = (const unsigned int*)(part + ((size_t)(0 * 16 + yy) * 2048 + b0 + bloc) * 192);
    const unsigned int* r1 = (const unsigned int*)(part + ((size_t)(1 * 16 + yy) * 2048 + b0 + bloc) * 192);
    float* dst = lds + (bloc * 16 + yy) * 180;
#pragma unroll
    for (int t = 0; t < 22; t++) {
      int d = s * 22 + t;
      if (d < 88) {
        unsigned int u0 = r0[d], u1 = r1[d];
        int n0 = d * 2;
        dst[n0]     = bf2f((unsigned short)(u0 & 0xFFFF)) + bf2f((unsigned short)(u1 & 0xFFFF));
        dst[n0 + 1] = bf2f((unsigned short)(u0 >> 16)) + bf2f((unsigned short)(u1 >> 16));
      }
    }
  }
  __syncthreads();
  for (int jj = tid; jj < 768; jj += 256) {
    int e = (jj * 683) >> 17;              // jj / 192
    int i = jj - e * 192;
    int bb = b0 + e;
    unsigned short* hb = harmbpre + (((bb >> 5) * 12 + (i >> 4)) << 9)
                       + ((i >> 3) & 1) * 256 + (bb & 31) * 8 + (i & 7);
    if (i < 165) {
      const float* row0 = lds + e * (16 * 180);
      int lv, rel; decode_i(i, lv, rel);
      int d = 2 * lv + 1;
      int off = i - rel;
      int v = divq(rel, lv), m = rel - v * d;
      float s = 0.f;
      for (int ch = 0; ch < 16; ch++) {
        const float* rw = row0 + ch * 180 + off;
        const float* p2 = p2s + ch * 165 + off;
        for (int u = 0; u < d; u++) s += rw[u * d + m] * p2[u * d + v];
      }
      s *= 0.25f * rsqrtf((float)d);
      harm_out[bb * 165 + i] = s;
      *hb = f2bf(s);
    } else {
      *hb = 0;
    }
  }
}

// ---------------- eval GEMM: bf16 logits in-place (row r -> first 9216B of its f32 slot) ----------------
__global__ __launch_bounds__(64) void eval_k(
    const unsigned short* __restrict__ harmbpre,
    const unsigned short* __restrict__ ewpre,
    float* __restrict__ probs,          // logitsB overlay: row r at byte r*18432
    float* __restrict__ logit0)
{
  const int l = threadIdx.x;
  const int hl = l >> 5, ln = l & 31;
  const int mt = blockIdx.y;
  const int n0 = blockIdx.x * 192;

  bf16x8 a[12];
  const short* ap = (const short*)harmbpre + mt * 6144 + l * 8;
#pragma unroll
  for (int kf = 0; kf < 12; kf++) a[kf] = *(const bf16x8*)(ap + kf * 512);

  f32x16 acc[6];
#pragma unroll
  for (int nf = 0; nf < 6; nf++) acc[nf] = ZERO16;

  const short* bp = (const short*)ewpre + (blockIdx.x * 6) * 6144 + l * 8;
#pragma unroll
  for (int kf = 0; kf < 12; kf++) {
#pragma unroll
    for (int nf = 0; nf < 6; nf++) {
      bf16x8 b = *(const bf16x8*)(bp + nf * 6144 + kf * 512);
      acc[nf] = __builtin_amdgcn_mfma_f32_32x32x16_bf16(a[kf], b, acc[nf], 0, 0, 0);
    }
  }
#pragma unroll
  for (int nf = 0; nf < 6; nf++) {
    const int col = n0 + nf * 32 + ln;
#pragma unroll
    for (int r = 0; r < 16; r++) {
      int row = (r & 3) + 8 * (r >> 2) + 4 * hl;
      unsigned short* lr = (unsigned short*)((char*)probs + (size_t)(mt * 32 + row) * 18432);
      lr[col] = f2bf(acc[nf][r]);
    }
  }
  if (mt == 0 && hl == 0) {
#pragma unroll
    for (int nf = 0; nf < 6; nf++) logit0[n0 + nf * 32 + ln] = acc[nf][0];
  }
}

// ---------------- fifth prob from logit0 (single block; exact f32 — R8-proven) ----------------
__global__ __launch_bounds__(256) void fifth_k(const float* __restrict__ logit0,
                                               float* __restrict__ fifth) {
  __shared__ float buf[4608];
  __shared__ float sm[4], ss[4];
  __shared__ float wv[4]; __shared__ int wi[4];
  __shared__ float gbest;
  const int tid = threadIdx.x;
  const int l = tid & 63, w = tid >> 6;
  float v[18];
  float mx = -3.4e38f;
#pragma unroll
  for (int i = 0; i < 18; i++) {
    v[i] = logit0[i * 256 + tid];
    buf[i * 256 + tid] = v[i];
    mx = fmaxf(mx, v[i]);
  }
#pragma unroll
  for (int off = 32; off >= 1; off >>= 1) mx = fmaxf(mx, __shfl_xor(mx, off));
  if (l == 0) sm[w] = mx;
  __syncthreads();
  mx = fmaxf(fmaxf(sm[0], sm[1]), fmaxf(sm[2], sm[3]));
  float s = 0.f;
#pragma unroll
  for (int i = 0; i < 18; i++) s += __expf(v[i] - mx);
#pragma unroll
  for (int off = 32; off >= 1; off >>= 1) s += __shfl_xor(s, off);
  if (l == 0) ss[w] = s;
  __syncthreads();
  s = ss[0] + ss[1] + ss[2] + ss[3];
  float inv = 1.f / s;

  float ff = 0.f;
  for (int it = 0; it < 5; it++) {
    float bm = -3.4e38f; int bi = 0;
    for (int i = tid; i < 4608; i += 256) {
      float xx = buf[i];
      if (xx > bm) { bm = xx; bi = i; }
    }
    for (int off = 32; off >= 1; off >>= 1) {
      float ov = __shfl_xor(bm, off); int oi = __shfl_xor(bi, off);
      if (ov > bm) { bm = ov; bi = oi; }
    }
    if (l == 0) { wv[w] = bm; wi[w] = bi; }
    __syncthreads();
    if (tid == 0) {
      float B = wv[0]; int I = wi[0];
      for (int k = 1; k < 4; k++) if (wv[k] > B) { B = wv[k]; I = wi[k]; }
      gbest = B;
      buf[I] = -3.4e38f;
    }
    __syncthreads();
    ff = gbest;
    __syncthreads();
  }
  if (tid == 0) *fifth = __expf(ff - mx) * inv;
}

// ---------------- fused softmax + threshold: bf16 row in, f32 probs out (same slot) ----------------
// Block r reads its ENTIRE bf16 row into registers before the first __syncthreads;
// all writes happen after -> self-overlap safe, zero cross-block overlap.
__global__ __launch_bounds__(256) void smthresh_k(float* __restrict__ probs,
                                                  const float* __restrict__ fifth) {
  char* rowbase = (char*)probs + (size_t)blockIdx.x * 18432;
  const unsigned int* lr = (const unsigned int*)rowbase;   // 2304 uints = 4608 bf16
  const int tid = threadIdx.x;
  const int l = tid & 63, w = tid >> 6;
  __shared__ float sm[4], ss[4];
  float v[18];
  float mx = -3.4e38f;
#pragma unroll
  for (int i = 0; i < 9; i++) {
    unsigned int u = lr[i * 256 + tid];
    float a = bf2f((unsigned short)(u & 0xFFFF));
    float b = bf2f((unsigned short)(u >> 16));
    v[2 * i] = a; v[2 * i + 1] = b;
    mx = fmaxf(mx, fmaxf(a, b));
  }
#pragma unroll
  for (int off = 32; off >= 1; off >>= 1) mx = fmaxf(mx, __shfl_xor(mx, off));
  if (l == 0) sm[w] = mx;
  __syncthreads();
  mx = fmaxf(fmaxf(sm[0], sm[1]), fmaxf(sm[2], sm[3]));
  float s = 0.f;
#pragma unroll
  for (int i = 0; i < 18; i++) { v[i] = __expf(v[i] - mx); s += v[i]; }
#pragma unroll
  for (int off = 32; off >= 1; off >>= 1) s += __shfl_xor(s, off);
  if (l == 0) ss[w] = s;
  __syncthreads();
  s = ss[0] + ss[1] + ss[2] + ss[3];
  float inv = 1.f / s;
  float t = *fifth;
  float2* pw = (float2*)rowbase;
#pragma unroll
  for (int i = 0; i < 9; i++) {
    float2 r;
    r.x = v[2 * i] * inv;     r.x = (r.x < t) ? 0.f : r.x;
    r.y = v[2 * i + 1] * inv; r.y = (r.y < t) ? 0.f : r.y;
    pw[i * 256 + tid] = r;
  }
}

extern "C" void kernel_launch(void* const* d_in, const int* in_sizes, int n_in,
                              void* d_out, int out_size, void* d_ws, size_t ws_size,
                              hipStream_t stream) {
  const float* x     = (const float*)d_in[0];
  const float* w_s2  = (const float*)d_in[1];
  const float* Y     = (const float*)d_in[2];
  const float* w_so3 = (const float*)d_in[3];
  const float* Dk    = (const float*)d_in[4];
  const float* Da    = (const float*)d_in[5];
  const float* ew    = (const float*)d_in[6];

  float* out = (float*)d_out;
  float* harm_out = out;                 // 2048*165
  float* probs    = out + 337920;        // 2048*4608 (partials -> bf16 logits -> probs)
  unsigned short* part = (unsigned short*)probs;   // 32 slices = 25.2 MB

  char* ws = (char*)d_ws;
  float* psi2  = (float*)(ws + 0);                         // 10,560 B
  float* fifth = (float*)(ws + 10560);                     // 4 B
  unsigned short* e1pre    = (unsigned short*)(ws + 12288);      // 4,194,304 B
  unsigned short* d2pre    = (unsigned short*)(ws + 4206592);    // 1,572,864 B
  unsigned short* ewpre    = (unsigned short*)(ws + 5779456);    // 1,769,472 B
  unsigned short* harmbpre = (unsigned short*)(ws + 7548928);    // 786,432 B
  float* logit0 = (float*)(ws + 8335360);                        // 18,432 B (~8.35 MB)

  prep_k<<<595, 256, 0, stream>>>(Da, ew, Y, w_s2, Dk, w_so3, e1pre, d2pre, ewpre, psi2);
  fused_mlp_k<<<512, 256, 0, stream>>>(x, e1pre, d2pre, part);
  so3_k<<<512, 256, 0, stream>>>(part, psi2, harm_out, harmbpre);
  eval_k<<<dim3(24, 64), 64, 0, stream>>>(harmbpre, ewpre, probs, logit0);
  fifth_k<<<1, 256, 0, stream>>>(logit0, fifth);
  smthresh_k<<<2048, 256, 0, stream>>>(probs, fifth);
}